// Round 1
// 5697.383 us; speedup vs baseline: 1.0014x; 1.0014x over previous
//
#include <hip/hip_runtime.h>
#include <math.h>
#include <stdint.h>

#define NIMG 16
#define A_TOTAL 8732
#define NCLS 80
#define TL_CLS 81
#define CANVASF 300.0f
#define SCORE_THR 0.01f
#define IOU_THRF 0.45f
#define KCAND 400
#define KOUT 200
#define CAND_CAP 4096
#define NBIN 65536

typedef double d4 __attribute__((ext_vector_type(4)));

__device__ __forceinline__ float clampf(float v, float lo, float hi) {
    return fminf(fmaxf(v, lo), hi);
}

// ---------------------------------------------------------------------------
// Fused conv dispatch.
//  - cls heads (95% of FLOPs): f64 MFMA path, REWRITTEN this round:
//      * weights pre-transposed to [k'][m] with k' = (ky*3+kx)*Cin + ci so
//        im2col addressing is ci = k & (Cin-1); (ky,kx) constant per segment.
//      * f32 LDS (cvt to f64 at register load), double-buffered, BK=16,
//        ONE barrier per K-block, 32 MFMA per barrier (BM=128, wave=32mx64n).
//      * conflict-free LDS: A rows stride 136 dwords (==8 mod 32), B stored
//        n-interleaved (pos = (n&15)*4 + (n>>4), stride 72) -> one
//        ds_read_b128 yields all 4 B operands per 8-MFMA group.
//      * global loads for block k+1 issued before MFMAs of block k.
//  - reg heads (5%): VALU f64 path, unchanged (proven bit-exact).
// f64 accumulation preserved everywhere (bit-exactness requirement).
// ---------------------------------------------------------------------------
struct ConvJobs {
    const float* feat[12];
    const float* wgt[12];
    const float* bias[12];
    float*       outp[12];
    int Cin[12], lgC[12], Hdim[12], M[12], Mp[12], tl[12], an[12], off[12], tm[12];
    int blkStart[12], nTiles[12];
    int nJobs;
    int pad;
};

struct TransJobs {
    const float* src[6];
    float* dst[6];
    int Cin[6], lgC[6], M[6], Mp[6], K[6], start[6];
};

// ---- one-off: cls weight transpose OIHW[m][ci][ky][kx] -> [k'=(r*Cin+ci)][m]
__global__ __launch_bounds__(256) void transpose_wgt(TransJobs tj, int total)
{
    for (int idx = blockIdx.x * blockDim.x + threadIdx.x; idx < total;
         idx += gridDim.x * blockDim.x) {
        int L = 0;
        while (L + 1 < 6 && idx >= tj.start[L + 1]) L++;
        int e = idx - tj.start[L];
        int k = e >> 9;
        int m = e & 511;
        int Mp = tj.Mp[L];
        if (m >= Mp) continue;
        int ci = k & (tj.Cin[L] - 1);
        int r = k >> tj.lgC[L];
        float v = 0.0f;
        if (m < tj.M[L]) v = tj.src[L][(size_t)m * tj.K[L] + (size_t)ci * 9 + r];
        tj.dst[L][(size_t)k * Mp + m] = v;
    }
}

// ---- cls path: f64 MFMA, BM=128 (4 waves x 32m), BN=64, BK=16, dbuf f32 LDS
__device__ __forceinline__ void conv_body_mfma(
    const float* __restrict__ feat, const float* __restrict__ wgtT,
    const float* __restrict__ bias, float* __restrict__ outbuf,
    int Cin, int lgC, int Hd, int M, int Mp, int an, int lvl_off,
    int n0, int m0, double* smem)
{
    const int K = Cin * 9;
    const int KB = K >> 4;
    const int HW = Hd * Hd;
    const int N = NIMG * HW;
    const int tid = threadIdx.x;
    const int wave = tid >> 6;
    const int lane = tid & 63;
    const int lm = lane & 15;
    const int lk = lane >> 4;

    // LDS layout: A f32 [2][16][136] (17408 B) then B f32 [2][16][72] (9216 B)
    float (*As)[16][136] = (float (*)[16][136])smem;
    float (*Bs)[16][72]  = (float (*)[16][72])(smem + 2176);

    // layout self-calibration (proven): recover (row, col) per acc slot
    int rowIdx[4], colIdx[4];
    {
        d4 z = (d4){0.0, 0.0, 0.0, 0.0};
        d4 pr = __builtin_amdgcn_mfma_f64_16x16x4f64((double)lm, 1.0, z, 0, 0, 0);
        d4 pc = __builtin_amdgcn_mfma_f64_16x16x4f64(1.0, (double)lm, z, 0, 0, 0);
#pragma unroll
        for (int i = 0; i < 4; i++) {
            rowIdx[i] = (int)(pr[i] * 0.25 + 0.5);
            colIdx[i] = (int)(pc[i] * 0.25 + 0.5);
        }
    }

    // B staging ids: thread stages k = wave*4 + e (e=0..3) at column bn
    const int bn = tid & 63;
    const int bpos = ((bn & 15) << 2) | (bn >> 4);   // n-interleaved position
    const int bk = wave << 2;
    const int ng = n0 + bn;
    const bool nvalid = ng < N;
    int bimg = 0, y0 = 0, x0 = 0;
    if (nvalid) { bimg = ng / HW; int p = ng - bimg * HW; y0 = p / Hd; x0 = p - y0 * Hd; }
    const float* fimg = feat + (size_t)bimg * Cin * HW;

    // A staging ids: thread stages float4 at rows ak, ak+8, cols am..am+3
    const int am = (tid & 31) << 2;
    const int ak = tid >> 5;
    const bool mval = (m0 + am) < Mp;   // Mp multiple of 4 -> whole float4 ok

    d4 acc[2][4];
#pragma unroll
    for (int mi = 0; mi < 2; mi++)
#pragma unroll
        for (int c = 0; c < 4; c++) acc[mi][c] = (d4){0.0, 0.0, 0.0, 0.0};

    float4 a_r0, a_r1;
    float b_r0, b_r1, b_r2, b_r3;
    int rcur = -1;
    bool bvalid = false;
    int rowoff = 0;

    auto stage = [&](int k0) {
        int r = k0 >> lgC;
        if (r != rcur) {
            rcur = r;
            int ky = (r * 171) >> 9;
            int kx = r - ky * 3;
            int yy = y0 + ky - 1;
            int xx = x0 + kx - 1;
            bvalid = nvalid && yy >= 0 && yy < Hd && xx >= 0 && xx < Hd;
            rowoff = bvalid ? (yy * Hd + xx) : 0;
        }
        const float* p = fimg + (size_t)((k0 & (Cin - 1)) + bk) * HW + rowoff;
        b_r0 = bvalid ? p[0] : 0.0f;
        b_r1 = bvalid ? p[HW] : 0.0f;
        b_r2 = bvalid ? p[2 * HW] : 0.0f;
        b_r3 = bvalid ? p[3 * HW] : 0.0f;
        if (mval) {
            const float* ap = wgtT + (size_t)(k0 + ak) * Mp + m0 + am;
            a_r0 = *(const float4*)ap;
            a_r1 = *(const float4*)(ap + 8 * (size_t)Mp);
        } else {
            a_r0 = make_float4(0.f, 0.f, 0.f, 0.f);
            a_r1 = a_r0;
        }
    };

    auto write_lds = [&](int buf) {
        *(float4*)&As[buf][ak][am] = a_r0;
        *(float4*)&As[buf][ak + 8][am] = a_r1;
        Bs[buf][bk + 0][bpos] = b_r0;
        Bs[buf][bk + 1][bpos] = b_r1;
        Bs[buf][bk + 2][bpos] = b_r2;
        Bs[buf][bk + 3][bpos] = b_r3;
    };

    const int wcol = (wave << 5) + lm;
    auto compute = [&](int buf) {
#pragma unroll
        for (int ks = 0; ks < 16; ks += 4) {
            double a0 = (double)As[buf][ks + lk][wcol];
            double a1 = (double)As[buf][ks + lk][wcol + 16];
            float4 bq = *(const float4*)&Bs[buf][ks + lk][lm << 2];
            double b0 = (double)bq.x;
            double b1 = (double)bq.y;
            double b2 = (double)bq.z;
            double b3 = (double)bq.w;
            acc[0][0] = __builtin_amdgcn_mfma_f64_16x16x4f64(a0, b0, acc[0][0], 0, 0, 0);
            acc[1][0] = __builtin_amdgcn_mfma_f64_16x16x4f64(a1, b0, acc[1][0], 0, 0, 0);
            acc[0][1] = __builtin_amdgcn_mfma_f64_16x16x4f64(a0, b1, acc[0][1], 0, 0, 0);
            acc[1][1] = __builtin_amdgcn_mfma_f64_16x16x4f64(a1, b1, acc[1][1], 0, 0, 0);
            acc[0][2] = __builtin_amdgcn_mfma_f64_16x16x4f64(a0, b2, acc[0][2], 0, 0, 0);
            acc[1][2] = __builtin_amdgcn_mfma_f64_16x16x4f64(a1, b2, acc[1][2], 0, 0, 0);
            acc[0][3] = __builtin_amdgcn_mfma_f64_16x16x4f64(a0, b3, acc[0][3], 0, 0, 0);
            acc[1][3] = __builtin_amdgcn_mfma_f64_16x16x4f64(a1, b3, acc[1][3], 0, 0, 0);
        }
    };

    // pipeline: stage(k+1) -> compute(k) -> write_lds(k+1) -> barrier
    stage(0);
    write_lds(0);
    __syncthreads();
    int cur = 0;
    for (int kb = 0; kb < KB; kb++) {
        if (kb + 1 < KB) stage((kb + 1) << 4);
        compute(cur);
        if (kb + 1 < KB) write_lds(cur ^ 1);
        __syncthreads();
        cur ^= 1;
    }

    // epilogue: probe-derived (row, col) per slot; tl hardcoded 81 (cls only)
    const int wm0 = m0 + (wave << 5);
#pragma unroll
    for (int mi = 0; mi < 2; mi++)
#pragma unroll
    for (int c = 0; c < 4; c++)
#pragma unroll
    for (int i = 0; i < 4; i++) {
        int mg = wm0 + mi * 16 + rowIdx[i];
        int ng2 = n0 + c * 16 + colIdx[i];
        if (mg >= M || ng2 >= N) continue;
        int b = ng2 / HW;
        int p = ng2 - b * HW;
        int aidx = mg / 81;
        int t = mg - aidx * 81;
        int row = lvl_off + p * an + aidx;
        outbuf[((size_t)b * A_TOTAL + row) * TL_CLS + t] = (float)(acc[mi][c][i] + (double)bias[mg]);
    }
}

// ---- staging helper for reg path (unchanged, proven bit-exact) ----
__device__ __forceinline__ void stage_B(
    const float* __restrict__ fbase, bool nvalid, int y0, int x0,
    int Hd, int HW, int k0, int bk0, int bn, double (*Bsb)[68])
{
#pragma unroll
    for (int e = 0; e < 4; e++) {
        int kg = k0 + bk0 + e;
        float v = 0.0f;
        if (nvalid) {
            int ci = kg / 9;
            int r = kg - ci * 9;
            int ky = r / 3;
            int kx = r - ky * 3;
            int yy = y0 + ky - 1;
            int xx = x0 + kx - 1;
            if (yy >= 0 && yy < Hd && xx >= 0 && xx < Hd)
                v = fbase[(size_t)ci * HW + yy * Hd + xx];
        }
        Bsb[bk0 + e][bn] = (double)v;
    }
}

// ---- reg path: VALU f64, 16m x 64n (unchanged) ----
__device__ __forceinline__ void conv_body_valu(
    const float* __restrict__ feat, const float* __restrict__ wgt,
    const float* __restrict__ bias, float* __restrict__ outbuf,
    int Cin, int Hd, int M, int tl, int an, int lvl_off,
    int n0, int m0, double (*Asb)[68], double (*Bsb)[68])
{
    const int K = Cin * 9;
    const int HW = Hd * Hd;
    const int N = NIMG * HW;
    const int tid = threadIdx.x;
    const int tx = tid & 15;
    const int ty = tid >> 4;

    const int bn = tid & 63;
    const int bk0 = (tid >> 6) * 4;
    const int ng = n0 + bn;
    const bool nvalid = ng < N;
    int bimg = 0, y0 = 0, x0 = 0;
    if (nvalid) { bimg = ng / HW; int p = ng - bimg * HW; y0 = p / Hd; x0 = p - y0 * Hd; }
    const float* fbase = feat + (size_t)bimg * Cin * HW;

    double acc[4];
#pragma unroll
    for (int j = 0; j < 4; j++) acc[j] = 0.0;

    for (int k0 = 0; k0 < K; k0 += 16) {
        {
            int am = tid & 15;
            int ak = tid >> 4;
            int mg = m0 + am;
            float v = (mg < M) ? wgt[(size_t)mg * K + k0 + ak] : 0.0f;
            Asb[ak][am] = (double)v;
        }
        stage_B(fbase, nvalid, y0, x0, Hd, HW, k0, bk0, bn, Bsb);
        __syncthreads();
#pragma unroll
        for (int kk = 0; kk < 16; kk++) {
            double a = Asb[kk][ty];
            double b0 = Bsb[kk][tx + 0];
            double b1 = Bsb[kk][tx + 16];
            double b2 = Bsb[kk][tx + 32];
            double b3 = Bsb[kk][tx + 48];
            acc[0] = fma(a, b0, acc[0]);
            acc[1] = fma(a, b1, acc[1]);
            acc[2] = fma(a, b2, acc[2]);
            acc[3] = fma(a, b3, acc[3]);
        }
        __syncthreads();
    }

    int mg = m0 + ty;
    if (mg < M) {
        double bv = (double)bias[mg];
        int aidx = mg / tl;
        int t = mg - aidx * tl;
#pragma unroll
        for (int j = 0; j < 4; j++) {
            int ng2 = n0 + tx + 16 * j;
            if (ng2 >= N) continue;
            int b = ng2 / HW;
            int p = ng2 - b * HW;
            int row = lvl_off + p * an + aidx;
            outbuf[((size_t)b * A_TOTAL + row) * tl + t] = (float)(acc[j] + bv);
        }
    }
}

__global__ __launch_bounds__(256) void fused_conv(ConvJobs jobs)
{
    __shared__ double smem[3328];   // 26624 B: max(cls 26624, reg 17408)

    int bid = (int)blockIdx.x;
    int j = 0;
    while (j + 1 < jobs.nJobs && bid >= jobs.blkStart[j + 1]) j++;
    int rel = bid - jobs.blkStart[j];
    int nt = rel % jobs.nTiles[j];
    int mt = rel / jobs.nTiles[j];
    int n0 = nt * 64;

    if (jobs.tm[j] == 4) {
        conv_body_mfma(jobs.feat[j], jobs.wgt[j], jobs.bias[j], jobs.outp[j],
                       jobs.Cin[j], jobs.lgC[j], jobs.Hdim[j], jobs.M[j],
                       jobs.Mp[j], jobs.an[j], jobs.off[j], n0, mt * 128, smem);
    } else {
        double (*Asb)[68] = (double (*)[68])smem;
        double (*Bsb)[68] = (double (*)[68])(smem + 16 * 68);
        conv_body_valu(jobs.feat[j], jobs.wgt[j], jobs.bias[j], jobs.outp[j],
                       jobs.Cin[j], jobs.Hdim[j], jobs.M[j], jobs.tl[j],
                       jobs.an[j], jobs.off[j], n0, mt * 16, Asb, Bsb);
    }
}

// ---------------------------------------------------------------------------
// Softmax over 81 classes (f64 internally), drop background class 0.
// ---------------------------------------------------------------------------
__global__ __launch_bounds__(256) void softmax_kernel(
    const float* __restrict__ cls, float* __restrict__ scr, int nrows)
{
    __shared__ float buf[64 * 81];
    __shared__ float inv[64];
    const int row0 = blockIdx.x * 64;
    const int tid = threadIdx.x;

    for (int i = tid; i < 64 * 81; i += 256) {
        int r = row0 + i / 81;
        buf[i] = (r < nrows) ? cls[(size_t)row0 * 81 + i] : 0.0f;
    }
    __syncthreads();
    if (tid < 64) {
        float m = -1e30f;
        for (int c = 0; c < 81; c++) m = fmaxf(m, buf[tid * 81 + c]);
        double md = (double)m;
        double ssum = 0.0;
        for (int c = 0; c < 81; c++) {
            double e = exp((double)buf[tid * 81 + c] - md);
            buf[tid * 81 + c] = (float)e;
            ssum += e;
        }
        inv[tid] = (float)(1.0 / ssum);
    }
    __syncthreads();
    for (int i = tid; i < 64 * 80; i += 256) {
        int r = i / 80;
        int c = i - r * 80;
        int gr = row0 + r;
        if (gr < nrows) scr[(size_t)gr * 80 + c] = buf[r * 81 + c + 1] * inv[r];
    }
}

// ---------------------------------------------------------------------------
__global__ void zero_kernel(unsigned int* __restrict__ p, int n)
{
    int i = blockIdx.x * blockDim.x + threadIdx.x;
    if (i < n) p[i] = 0u;
}

// ---------------------------------------------------------------------------
__global__ void hist_kernel(const float* __restrict__ scr, unsigned int* __restrict__ hist)
{
    const int per_img = A_TOTAL * NCLS;
    const size_t total = (size_t)NIMG * per_img;
    for (size_t i = (size_t)blockIdx.x * blockDim.x + threadIdx.x; i < total;
         i += (size_t)gridDim.x * blockDim.x) {
        float v = scr[i];
        if (v > SCORE_THR) {
            int img = (int)(i / per_img);
            unsigned int u = __float_as_uint(v);
            atomicAdd(&hist[img * NBIN + (u >> 16)], 1u);
        }
    }
}

// ---------------------------------------------------------------------------
__global__ __launch_bounds__(1024) void select_kernel(
    const unsigned int* __restrict__ hist, unsigned int* __restrict__ sel)
{
    __shared__ unsigned int vals[1024];
    __shared__ unsigned int red[1024];
    __shared__ int s_total, s_b0, s_done;
    const int img = blockIdx.x;
    const int tid = threadIdx.x;
    if (tid == 0) { s_total = 0; s_b0 = 0; s_done = 0; }
    __syncthreads();
    for (int c = 63; c >= 0; c--) {
        unsigned int h = hist[img * NBIN + c * 1024 + tid];
        vals[tid] = h;
        red[tid] = h;
        __syncthreads();
        for (int s = 512; s > 0; s >>= 1) {
            if (tid < s) red[tid] += red[tid + s];
            __syncthreads();
        }
        if (tid == 0 && !s_done) {
            if (s_total + (int)red[0] >= KCAND) {
                int cum = s_total;
                for (int tt = 1023; tt >= 0; tt--) {
                    cum += (int)vals[tt];
                    if (cum >= KCAND) { s_b0 = c * 1024 + tt; s_done = 1; break; }
                }
            } else {
                s_total += (int)red[0];
            }
        }
        __syncthreads();
        if (s_done) break;
    }
    if (tid == 0) sel[img] = (unsigned int)s_b0;
}

// ---------------------------------------------------------------------------
__global__ void gather_kernel(const float* __restrict__ scr,
                              const unsigned int* __restrict__ sel,
                              unsigned int* __restrict__ candcnt,
                              uint2* __restrict__ cand)
{
    const int per_img = A_TOTAL * NCLS;
    const size_t total = (size_t)NIMG * per_img;
    for (size_t i = (size_t)blockIdx.x * blockDim.x + threadIdx.x; i < total;
         i += (size_t)gridDim.x * blockDim.x) {
        float v = scr[i];
        if (v > SCORE_THR) {
            int img = (int)(i / per_img);
            unsigned int u = __float_as_uint(v);
            if ((u >> 16) >= sel[img]) {
                unsigned int pos = atomicAdd(&candcnt[img], 1u);
                if (pos < CAND_CAP) {
                    unsigned int ridx = (unsigned int)(i - (size_t)img * per_img);
                    cand[(size_t)img * CAND_CAP + pos] = make_uint2(u, ridx);
                }
            }
        }
    }
}

// ---------------------------------------------------------------------------
__global__ __launch_bounds__(1024) void nms_kernel(
    const uint2* __restrict__ cand, const unsigned int* __restrict__ candcnt,
    const float* __restrict__ reg_all, const float* __restrict__ priors,
    float* __restrict__ out)
{
    __shared__ unsigned long long key[CAND_CAP];
    __shared__ float s_sc[KCAND];
    __shared__ float s_bx[KCAND][4];
    __shared__ float s_ob[KCAND][4];
    __shared__ float s_ar[KCAND];
    __shared__ float s_cl[KCAND];
    __shared__ int s_keep[KCAND];
    __shared__ int s_fi[KOUT];

    const int img = blockIdx.x;
    const int tid = threadIdx.x;
    unsigned int craw = candcnt[img];
    const int cnt = (craw > CAND_CAP) ? CAND_CAP : (int)craw;

    for (int i = tid; i < CAND_CAP; i += 1024) {
        unsigned long long kv = 0ull;
        if (i < cnt) {
            uint2 e = cand[(size_t)img * CAND_CAP + i];
            kv = ((unsigned long long)e.x << 32) | (unsigned int)(~e.y);
        }
        key[i] = kv;
    }
    __syncthreads();

    for (int ksz = 2; ksz <= CAND_CAP; ksz <<= 1) {
        for (int jj = ksz >> 1; jj > 0; jj >>= 1) {
            for (int i = tid; i < CAND_CAP; i += 1024) {
                int p = i ^ jj;
                if (p > i) {
                    bool desc = ((i & ksz) == 0);
                    unsigned long long a = key[i];
                    unsigned long long b = key[p];
                    bool sw = desc ? (a < b) : (a > b);
                    if (sw) { key[i] = b; key[p] = a; }
                }
            }
            __syncthreads();
        }
    }

    const float CLIPF = 4.135166556742356f;
    if (tid < KCAND) {
        const int j = tid;
        float s = 0.0f;
        unsigned int idx = 0u;
        if (j < cnt) {
            unsigned long long kv = key[j];
            unsigned int bits = (unsigned int)(kv >> 32);
            idx = ~((unsigned int)kv);
            s = __uint_as_float(bits);
        }
        int anc = (int)(idx / NCLS);
        int cl = (int)(idx - (unsigned int)anc * NCLS) + 1;
        const float* d = reg_all + ((size_t)img * A_TOTAL + anc) * 4;
        const float* pr = priors + (size_t)anc * 4;
        float d0 = d[0], d1 = d[1], d2 = d[2], d3 = d[3];
        float p0 = pr[0], p1 = pr[1], p2 = pr[2], p3 = pr[3];
        float cx = p0 + d0 * 0.1f * p2;
        float cy = p1 + d1 * 0.1f * p3;
        float t2 = fminf(d2 * 0.2f, CLIPF);
        float t3 = fminf(d3 * 0.2f, CLIPF);
        float bw = p2 * (float)exp((double)t2);
        float bh = p3 * (float)exp((double)t3);
        float x1 = clampf(cx - 0.5f * bw, 0.0f, CANVASF);
        float y1 = clampf(cy - 0.5f * bh, 0.0f, CANVASF);
        float x2 = clampf(cx + 0.5f * bw, 0.0f, CANVASF);
        float y2 = clampf(cy + 0.5f * bh, 0.0f, CANVASF);
        bool valid = (s > 0.0f) && (x2 > x1) && (y2 > y1);
        s = valid ? s : 0.0f;
        float off = (float)cl * (CANVASF + 1.0f);
        float ox1 = x1 + off, oy1 = y1 + off, ox2 = x2 + off, oy2 = y2 + off;
        s_sc[j] = s;
        s_cl[j] = (float)cl;
        s_keep[j] = valid ? 1 : 0;
        s_bx[j][0] = x1; s_bx[j][1] = y1; s_bx[j][2] = x2; s_bx[j][3] = y2;
        s_ob[j][0] = ox1; s_ob[j][1] = oy1; s_ob[j][2] = ox2; s_ob[j][3] = oy2;
        s_ar[j] = (ox2 - ox1) * (oy2 - oy1);
    }
    __syncthreads();

    for (int i = 0; i < KCAND; i++) {
        int ki = s_keep[i];
        if (ki && tid < KCAND && tid > i) {
            float lx = fmaxf(s_ob[i][0], s_ob[tid][0]);
            float ly = fmaxf(s_ob[i][1], s_ob[tid][1]);
            float rx = fminf(s_ob[i][2], s_ob[tid][2]);
            float ry = fminf(s_ob[i][3], s_ob[tid][3]);
            float iw = fmaxf(rx - lx, 0.0f);
            float ih = fmaxf(ry - ly, 0.0f);
            float inter = iw * ih;
            float iou = inter / (s_ar[i] + s_ar[tid] - inter + 1e-9f);
            if (iou > IOU_THRF) s_keep[tid] = 0;
        }
        __syncthreads();
    }

    if (tid == 0) {
        int pos = 0;
        for (int j = 0; j < KCAND && pos < KOUT; j++)
            if (s_keep[j]) s_fi[pos++] = j;
        for (int j = 0; j < KCAND && pos < KOUT; j++)
            if (!s_keep[j]) s_fi[pos++] = j;
    }
    __syncthreads();

    if (tid < KOUT) {
        int j = s_fi[tid];
        float fs = s_keep[j] ? s_sc[j] : 0.0f;
        size_t o = (size_t)img * KOUT + tid;
        out[o * 4 + 0] = s_bx[j][0];
        out[o * 4 + 1] = s_bx[j][1];
        out[o * 4 + 2] = s_bx[j][2];
        out[o * 4 + 3] = s_bx[j][3];
        out[(size_t)NIMG * KOUT * 4 + o] = fs;
        out[(size_t)NIMG * KOUT * 5 + o] = (fs > 0.0f) ? s_cl[j] : 0.0f;
    }
}

// ---------------------------------------------------------------------------
extern "C" void kernel_launch(void* const* d_in, const int* in_sizes, int n_in,
                              void* d_out, int out_size, void* d_ws, size_t ws_size,
                              hipStream_t stream)
{
    static const int Cin_[6] = {512, 1024, 512, 256, 256, 256};
    static const int lgC_[6] = {9, 10, 9, 8, 8, 8};
    static const int HW_[6]  = {38, 19, 10, 5, 3, 1};
    static const int an_[6]  = {4, 6, 6, 6, 4, 4};
    static const int off_[6] = {0, 5776, 7942, 8542, 8692, 8728};
    static const int Mp_[6]  = {324, 488, 488, 488, 324, 324};
    static const size_t wtoff_[6] = {0, 1492992, 5990400, 8239104, 9363456, 10109952};

    char* ws = (char*)d_ws;
    const size_t OFF_CLS  = 0;
    const size_t OFF_SCR  = 45266688;
    const size_t OFF_REG  = 89974528;
    const size_t OFF_HIST = 92209920;
    const size_t OFF_CCNT = 96404224;
    const size_t OFF_SEL  = 96404288;
    const size_t OFF_CAND = 96404352;

    float* cls_all = (float*)(ws + OFF_CLS);
    float* scr     = (float*)(ws + OFF_SCR);
    float* reg_all = (float*)(ws + OFF_REG);
    unsigned int* hist    = (unsigned int*)(ws + OFF_HIST);
    unsigned int* candcnt = (unsigned int*)(ws + OFF_CCNT);
    unsigned int* sel     = (unsigned int*)(ws + OFF_SEL);
    uint2* cand           = (uint2*)(ws + OFF_CAND);

    // transposed cls weights live in the scr region (43.4 MB <= 44.7 MB);
    // scr is fully overwritten by softmax_kernel AFTER fused_conv completes.
    float* wT = scr;

    {
        int nz = NIMG * NBIN + 16 + 16;
        zero_kernel<<<(nz + 255) / 256, 256, 0, stream>>>(hist, nz);
    }

    // one-off weight transpose for the 6 cls heads
    {
        TransJobs tj;
        int tstart = 0;
        for (int L = 0; L < 6; L++) {
            tj.src[L] = (const float*)d_in[L * 5 + 1];
            tj.dst[L] = wT + wtoff_[L];
            tj.Cin[L] = Cin_[L];
            tj.lgC[L] = lgC_[L];
            tj.M[L] = an_[L] * TL_CLS;
            tj.Mp[L] = Mp_[L];
            tj.K[L] = Cin_[L] * 9;
            tj.start[L] = tstart;
            tstart += Cin_[L] * 9 * 512;
        }
        transpose_wgt<<<4096, 256, 0, stream>>>(tj, tstart);
    }

    ConvJobs jobs;
    static const int ord_lvl[12]  = {1, 0, 1, 0, 2, 2, 3, 3, 4, 4, 5, 5};
    static const int ord_iscls[12]= {1, 1, 0, 0, 1, 0, 1, 0, 1, 0, 1, 0};
    int blk = 0;
    for (int q = 0; q < 12; q++) {
        int L = ord_lvl[q];
        int iscls = ord_iscls[q];
        int an = an_[L];
        jobs.feat[q] = (const float*)d_in[L * 5 + 0];
        jobs.wgt[q]  = iscls ? (const float*)(wT + wtoff_[L])
                             : (const float*)d_in[L * 5 + 3];
        jobs.bias[q] = (const float*)d_in[L * 5 + (iscls ? 2 : 4)];
        jobs.outp[q] = iscls ? cls_all : reg_all;
        jobs.Cin[q]  = Cin_[L];
        jobs.lgC[q]  = lgC_[L];
        jobs.Hdim[q] = HW_[L];
        jobs.M[q]    = an * (iscls ? TL_CLS : 4);
        jobs.Mp[q]   = iscls ? Mp_[L] : jobs.M[q];
        jobs.tl[q]   = iscls ? TL_CLS : 4;
        jobs.an[q]   = an;
        jobs.off[q]  = off_[L];
        jobs.tm[q]   = iscls ? 4 : 1;
        int N = NIMG * HW_[L] * HW_[L];
        int bm = iscls ? 128 : 16;
        int nT = (N + 63) / 64;
        int mT = (jobs.M[q] + bm - 1) / bm;
        jobs.blkStart[q] = blk;
        jobs.nTiles[q] = nT;
        blk += nT * mT;
    }
    jobs.nJobs = 12;
    jobs.pad = 0;

    fused_conv<<<blk, 256, 0, stream>>>(jobs);

    softmax_kernel<<<(NIMG * A_TOTAL + 63) / 64, 256, 0, stream>>>(cls_all, scr, NIMG * A_TOTAL);
    hist_kernel<<<2048, 256, 0, stream>>>(scr, hist);
    select_kernel<<<NIMG, 1024, 0, stream>>>(hist, sel);
    gather_kernel<<<2048, 256, 0, stream>>>(scr, sel, candcnt, cand);
    nms_kernel<<<NIMG, 1024, 0, stream>>>(cand, candcnt, reg_all,
                                          (const float*)d_in[30], (float*)d_out);
}

// Round 2
// 4647.203 us; speedup vs baseline: 1.2277x; 1.2260x over previous
//
#include <hip/hip_runtime.h>
#include <math.h>
#include <stdint.h>

#define NIMG 16
#define A_TOTAL 8732
#define NCLS 80
#define TL_CLS 81
#define CANVASF 300.0f
#define SCORE_THR 0.01f
#define IOU_THRF 0.45f
#define KCAND 400
#define KOUT 200
#define CAND_CAP 4096
#define NBIN 65536

typedef double d4 __attribute__((ext_vector_type(4)));

__device__ __forceinline__ float clampf(float v, float lo, float hi) {
    return fminf(fmaxf(v, lo), hi);
}

// ---------------------------------------------------------------------------
// Conv: LDS-free, barrier-free f64-MFMA waves.
//  - weights pre-transposed to [k'=(r*Cin+ci)][m] (cls: scr region; reg: hist
//    region, zeroed AFTER conv). Both MFMA operands loaded per-lane DIRECTLY
//    from global: A = wgtT[k*Mp+m], B = feat[bimg*CHW+ci*HW+rowoff(n)].
//  - each 64-lane wave owns an independent 32m x 64n tile (reg: 16m x 64n),
//    8 (4) f64 MFMAs per k-group of 4, 6 dword loads / 6 cvt per group,
//    2-deep software pipeline; NO __shared__, NO __syncthreads.
//  - k-order identical to round-1 (bit-identical cls outputs).
// ---------------------------------------------------------------------------
struct ConvJobs {
    const float* feat[12];
    const float* wgtT[12];
    const float* bias[12];
    float*       outp[12];
    int Cin[12], lgC[12], Hd[12], M[12], Mp[12], an[12], off[12], mi[12], tl[12];
    int tileStart[12], nT[12];
    int nJobs, totalTiles;
};

struct TransJobs {
    const float* src[12];
    float* dst[12];
    int Cin[12], lgC[12], M[12], Mp[12], K[12], start[12];
    int total;
};

// ---- weight transpose OIHW[m][ci][ky][kx] -> [k'=(r*Cin+ci)][m], zero-pad Mp
__global__ __launch_bounds__(256) void transpose_wgt(TransJobs tj)
{
    for (int idx = blockIdx.x * blockDim.x + threadIdx.x; idx < tj.total;
         idx += gridDim.x * blockDim.x) {
        int t = 0;
        while (t + 1 < 12 && idx >= tj.start[t + 1]) t++;
        int e = idx - tj.start[t];
        int k = e >> 9;
        int m = e & 511;
        if (m >= tj.Mp[t]) continue;
        int ci = k & (tj.Cin[t] - 1);
        int r = k >> tj.lgC[t];
        float v = (m < tj.M[t]) ? tj.src[t][(size_t)m * tj.K[t] + (size_t)ci * 9 + r] : 0.0f;
        tj.dst[t][(size_t)k * tj.Mp[t] + m] = v;
    }
}

// ---- per-wave conv tile: MI=2 -> 32m x 64n (cls), MI=1 -> 16m x 64n (reg)
template<int MI>
__device__ __forceinline__ void conv_wave(
    const float* __restrict__ feat, const float* __restrict__ wgtT,
    const float* __restrict__ bias, float* __restrict__ outbuf,
    int Cin, int lgC, int Hd, int M, int Mp, int an, int tl, int lvl_off,
    int n0, int m0)
{
    const int K = Cin * 9;
    const int HW = Hd * Hd;
    const int N = NIMG * HW;
    const int CHW = Cin * HW;
    const int lane = threadIdx.x & 63;
    const int lm = lane & 15;
    const int lk = lane >> 4;

    // layout self-calibration (proven): recover (row, col) per acc slot
    int rowIdx[4], colIdx[4];
    {
        d4 z = (d4){0.0, 0.0, 0.0, 0.0};
        d4 pr = __builtin_amdgcn_mfma_f64_16x16x4f64((double)lm, 1.0, z, 0, 0, 0);
        d4 pc = __builtin_amdgcn_mfma_f64_16x16x4f64(1.0, (double)lm, z, 0, 0, 0);
#pragma unroll
        for (int i = 0; i < 4; i++) {
            rowIdx[i] = (int)(pr[i] * 0.25 + 0.5);
            colIdx[i] = (int)(pc[i] * 0.25 + 0.5);
        }
    }

    const int gPerR = Cin >> 2;     // k-groups per kernel tap (power of 2)
    const int KBg = K >> 2;         // total k-groups (always even)

    int voffA = lk * Mp + m0 + lm;
    int voffB[4];
    float maskc[4];
    float bufA[2][2], bufB[2][4], bufM[2][4];

    d4 acc[2][4];
#pragma unroll
    for (int a = 0; a < 2; a++)
#pragma unroll
        for (int c = 0; c < 4; c++) acc[a][c] = (d4){0.0, 0.0, 0.0, 0.0};

    // recompute per-lane B offsets/masks at a tap boundary (9 times total)
    auto newR = [&](int r) {
        int ky = (r * 171) >> 9;    // r/3 for r<9
        int kx = r - 3 * ky;
#pragma unroll
        for (int c = 0; c < 4; c++) {
            int ng = n0 + lm + 16 * c;
            bool nv = ng < N;
            int bimg = 0, p = 0;
            if (nv) { bimg = ng / HW; p = ng - bimg * HW; }
            int y0 = p / Hd;
            int x0 = p - y0 * Hd;
            int yy = y0 + ky - 1;
            int xx = x0 + kx - 1;
            bool v = nv && (yy >= 0) && (yy < Hd) && (xx >= 0) && (xx < Hd);
            maskc[c] = v ? 1.0f : 0.0f;
            voffB[c] = bimg * CHW + lk * HW + (v ? (yy * Hd + xx) : 0);
        }
    };

    auto loadG = [&](int g, int slot) {
        if ((g & (gPerR - 1)) == 0) newR(g >> (lgC - 2));
#pragma unroll
        for (int c = 0; c < 4; c++) {
            bufB[slot][c] = feat[voffB[c]];
            bufM[slot][c] = maskc[c];
            voffB[c] += 4 * HW;
        }
        bufA[slot][0] = wgtT[voffA];
        if constexpr (MI == 2) bufA[slot][1] = wgtT[voffA + 16];
        voffA += 4 * Mp;
    };

    loadG(0, 0);
    loadG(1, 1);
    for (int g = 0; g < KBg; g += 2) {
        {
            double a0 = (double)bufA[0][0];
            double a1 = 0.0;
            if constexpr (MI == 2) a1 = (double)bufA[0][1];
            double b0 = (double)(bufB[0][0] * bufM[0][0]);
            double b1 = (double)(bufB[0][1] * bufM[0][1]);
            double b2 = (double)(bufB[0][2] * bufM[0][2]);
            double b3 = (double)(bufB[0][3] * bufM[0][3]);
            if (g + 2 < KBg) loadG(g + 2, 0);
            acc[0][0] = __builtin_amdgcn_mfma_f64_16x16x4f64(a0, b0, acc[0][0], 0, 0, 0);
            if constexpr (MI == 2)
                acc[1][0] = __builtin_amdgcn_mfma_f64_16x16x4f64(a1, b0, acc[1][0], 0, 0, 0);
            acc[0][1] = __builtin_amdgcn_mfma_f64_16x16x4f64(a0, b1, acc[0][1], 0, 0, 0);
            if constexpr (MI == 2)
                acc[1][1] = __builtin_amdgcn_mfma_f64_16x16x4f64(a1, b1, acc[1][1], 0, 0, 0);
            acc[0][2] = __builtin_amdgcn_mfma_f64_16x16x4f64(a0, b2, acc[0][2], 0, 0, 0);
            if constexpr (MI == 2)
                acc[1][2] = __builtin_amdgcn_mfma_f64_16x16x4f64(a1, b2, acc[1][2], 0, 0, 0);
            acc[0][3] = __builtin_amdgcn_mfma_f64_16x16x4f64(a0, b3, acc[0][3], 0, 0, 0);
            if constexpr (MI == 2)
                acc[1][3] = __builtin_amdgcn_mfma_f64_16x16x4f64(a1, b3, acc[1][3], 0, 0, 0);
        }
        {
            double a0 = (double)bufA[1][0];
            double a1 = 0.0;
            if constexpr (MI == 2) a1 = (double)bufA[1][1];
            double b0 = (double)(bufB[1][0] * bufM[1][0]);
            double b1 = (double)(bufB[1][1] * bufM[1][1]);
            double b2 = (double)(bufB[1][2] * bufM[1][2]);
            double b3 = (double)(bufB[1][3] * bufM[1][3]);
            if (g + 3 < KBg) loadG(g + 3, 1);
            acc[0][0] = __builtin_amdgcn_mfma_f64_16x16x4f64(a0, b0, acc[0][0], 0, 0, 0);
            if constexpr (MI == 2)
                acc[1][0] = __builtin_amdgcn_mfma_f64_16x16x4f64(a1, b0, acc[1][0], 0, 0, 0);
            acc[0][1] = __builtin_amdgcn_mfma_f64_16x16x4f64(a0, b1, acc[0][1], 0, 0, 0);
            if constexpr (MI == 2)
                acc[1][1] = __builtin_amdgcn_mfma_f64_16x16x4f64(a1, b1, acc[1][1], 0, 0, 0);
            acc[0][2] = __builtin_amdgcn_mfma_f64_16x16x4f64(a0, b2, acc[0][2], 0, 0, 0);
            if constexpr (MI == 2)
                acc[1][2] = __builtin_amdgcn_mfma_f64_16x16x4f64(a1, b2, acc[1][2], 0, 0, 0);
            acc[0][3] = __builtin_amdgcn_mfma_f64_16x16x4f64(a0, b3, acc[0][3], 0, 0, 0);
            if constexpr (MI == 2)
                acc[1][3] = __builtin_amdgcn_mfma_f64_16x16x4f64(a1, b3, acc[1][3], 0, 0, 0);
        }
    }

    // epilogue: probe-derived (row, col) per slot
#pragma unroll
    for (int mi2 = 0; mi2 < MI; mi2++)
#pragma unroll
    for (int c = 0; c < 4; c++)
#pragma unroll
    for (int i = 0; i < 4; i++) {
        int mg = m0 + mi2 * 16 + rowIdx[i];
        int ng2 = n0 + c * 16 + colIdx[i];
        if (mg >= M || ng2 >= N) continue;
        int b = ng2 / HW;
        int p = ng2 - b * HW;
        int aidx = mg / tl;
        int t = mg - aidx * tl;
        int row = lvl_off + p * an + aidx;
        outbuf[((size_t)b * A_TOTAL + row) * tl + t] = (float)(acc[mi2][c][i] + (double)bias[mg]);
    }
}

__global__ __launch_bounds__(256, 4) void fused_conv(ConvJobs J)
{
    int wave = threadIdx.x >> 6;
    int gid = (int)blockIdx.x * 4 + wave;
    if (gid >= J.totalTiles) return;
    int j = 0;
    while (j + 1 < J.nJobs && gid >= J.tileStart[j + 1]) j++;
    int rel = gid - J.tileStart[j];
    int nt = rel % J.nT[j];
    int mt = rel / J.nT[j];
    int n0 = nt * 64;

    if (J.mi[j] == 2)
        conv_wave<2>(J.feat[j], J.wgtT[j], J.bias[j], J.outp[j], J.Cin[j], J.lgC[j],
                     J.Hd[j], J.M[j], J.Mp[j], J.an[j], J.tl[j], J.off[j], n0, mt * 32);
    else
        conv_wave<1>(J.feat[j], J.wgtT[j], J.bias[j], J.outp[j], J.Cin[j], J.lgC[j],
                     J.Hd[j], J.M[j], J.Mp[j], J.an[j], J.tl[j], J.off[j], n0, mt * 16);
}

// ---------------------------------------------------------------------------
// Softmax over 81 classes (f64 internally), drop background class 0.
// ---------------------------------------------------------------------------
__global__ __launch_bounds__(256) void softmax_kernel(
    const float* __restrict__ cls, float* __restrict__ scr, int nrows)
{
    __shared__ float buf[64 * 81];
    __shared__ float inv[64];
    const int row0 = blockIdx.x * 64;
    const int tid = threadIdx.x;

    for (int i = tid; i < 64 * 81; i += 256) {
        int r = row0 + i / 81;
        buf[i] = (r < nrows) ? cls[(size_t)row0 * 81 + i] : 0.0f;
    }
    __syncthreads();
    if (tid < 64) {
        float m = -1e30f;
        for (int c = 0; c < 81; c++) m = fmaxf(m, buf[tid * 81 + c]);
        double md = (double)m;
        double ssum = 0.0;
        for (int c = 0; c < 81; c++) {
            double e = exp((double)buf[tid * 81 + c] - md);
            buf[tid * 81 + c] = (float)e;
            ssum += e;
        }
        inv[tid] = (float)(1.0 / ssum);
    }
    __syncthreads();
    for (int i = tid; i < 64 * 80; i += 256) {
        int r = i / 80;
        int c = i - r * 80;
        int gr = row0 + r;
        if (gr < nrows) scr[(size_t)gr * 80 + c] = buf[r * 81 + c + 1] * inv[r];
    }
}

// ---------------------------------------------------------------------------
__global__ void zero_kernel(unsigned int* __restrict__ p, int n)
{
    int i = blockIdx.x * blockDim.x + threadIdx.x;
    if (i < n) p[i] = 0u;
}

// ---------------------------------------------------------------------------
__global__ void hist_kernel(const float* __restrict__ scr, unsigned int* __restrict__ hist)
{
    const int per_img = A_TOTAL * NCLS;
    const size_t total = (size_t)NIMG * per_img;
    for (size_t i = (size_t)blockIdx.x * blockDim.x + threadIdx.x; i < total;
         i += (size_t)gridDim.x * blockDim.x) {
        float v = scr[i];
        if (v > SCORE_THR) {
            int img = (int)(i / per_img);
            unsigned int u = __float_as_uint(v);
            atomicAdd(&hist[img * NBIN + (u >> 16)], 1u);
        }
    }
}

// ---------------------------------------------------------------------------
__global__ __launch_bounds__(1024) void select_kernel(
    const unsigned int* __restrict__ hist, unsigned int* __restrict__ sel)
{
    __shared__ unsigned int vals[1024];
    __shared__ unsigned int red[1024];
    __shared__ int s_total, s_b0, s_done;
    const int img = blockIdx.x;
    const int tid = threadIdx.x;
    if (tid == 0) { s_total = 0; s_b0 = 0; s_done = 0; }
    __syncthreads();
    for (int c = 63; c >= 0; c--) {
        unsigned int h = hist[img * NBIN + c * 1024 + tid];
        vals[tid] = h;
        red[tid] = h;
        __syncthreads();
        for (int s = 512; s > 0; s >>= 1) {
            if (tid < s) red[tid] += red[tid + s];
            __syncthreads();
        }
        if (tid == 0 && !s_done) {
            if (s_total + (int)red[0] >= KCAND) {
                int cum = s_total;
                for (int tt = 1023; tt >= 0; tt--) {
                    cum += (int)vals[tt];
                    if (cum >= KCAND) { s_b0 = c * 1024 + tt; s_done = 1; break; }
                }
            } else {
                s_total += (int)red[0];
            }
        }
        __syncthreads();
        if (s_done) break;
    }
    if (tid == 0) sel[img] = (unsigned int)s_b0;
}

// ---------------------------------------------------------------------------
__global__ void gather_kernel(const float* __restrict__ scr,
                              const unsigned int* __restrict__ sel,
                              unsigned int* __restrict__ candcnt,
                              uint2* __restrict__ cand)
{
    const int per_img = A_TOTAL * NCLS;
    const size_t total = (size_t)NIMG * per_img;
    for (size_t i = (size_t)blockIdx.x * blockDim.x + threadIdx.x; i < total;
         i += (size_t)gridDim.x * blockDim.x) {
        float v = scr[i];
        if (v > SCORE_THR) {
            int img = (int)(i / per_img);
            unsigned int u = __float_as_uint(v);
            if ((u >> 16) >= sel[img]) {
                unsigned int pos = atomicAdd(&candcnt[img], 1u);
                if (pos < CAND_CAP) {
                    unsigned int ridx = (unsigned int)(i - (size_t)img * per_img);
                    cand[(size_t)img * CAND_CAP + pos] = make_uint2(u, ridx);
                }
            }
        }
    }
}

// ---------------------------------------------------------------------------
__global__ __launch_bounds__(1024) void nms_kernel(
    const uint2* __restrict__ cand, const unsigned int* __restrict__ candcnt,
    const float* __restrict__ reg_all, const float* __restrict__ priors,
    float* __restrict__ out)
{
    __shared__ unsigned long long key[CAND_CAP];
    __shared__ float s_sc[KCAND];
    __shared__ float s_bx[KCAND][4];
    __shared__ float s_ob[KCAND][4];
    __shared__ float s_ar[KCAND];
    __shared__ float s_cl[KCAND];
    __shared__ int s_keep[KCAND];
    __shared__ int s_fi[KOUT];

    const int img = blockIdx.x;
    const int tid = threadIdx.x;
    unsigned int craw = candcnt[img];
    const int cnt = (craw > CAND_CAP) ? CAND_CAP : (int)craw;

    for (int i = tid; i < CAND_CAP; i += 1024) {
        unsigned long long kv = 0ull;
        if (i < cnt) {
            uint2 e = cand[(size_t)img * CAND_CAP + i];
            kv = ((unsigned long long)e.x << 32) | (unsigned int)(~e.y);
        }
        key[i] = kv;
    }
    __syncthreads();

    for (int ksz = 2; ksz <= CAND_CAP; ksz <<= 1) {
        for (int jj = ksz >> 1; jj > 0; jj >>= 1) {
            for (int i = tid; i < CAND_CAP; i += 1024) {
                int p = i ^ jj;
                if (p > i) {
                    bool desc = ((i & ksz) == 0);
                    unsigned long long a = key[i];
                    unsigned long long b = key[p];
                    bool sw = desc ? (a < b) : (a > b);
                    if (sw) { key[i] = b; key[p] = a; }
                }
            }
            __syncthreads();
        }
    }

    const float CLIPF = 4.135166556742356f;
    if (tid < KCAND) {
        const int j = tid;
        float s = 0.0f;
        unsigned int idx = 0u;
        if (j < cnt) {
            unsigned long long kv = key[j];
            unsigned int bits = (unsigned int)(kv >> 32);
            idx = ~((unsigned int)kv);
            s = __uint_as_float(bits);
        }
        int anc = (int)(idx / NCLS);
        int cl = (int)(idx - (unsigned int)anc * NCLS) + 1;
        const float* d = reg_all + ((size_t)img * A_TOTAL + anc) * 4;
        const float* pr = priors + (size_t)anc * 4;
        float d0 = d[0], d1 = d[1], d2 = d[2], d3 = d[3];
        float p0 = pr[0], p1 = pr[1], p2 = pr[2], p3 = pr[3];
        float cx = p0 + d0 * 0.1f * p2;
        float cy = p1 + d1 * 0.1f * p3;
        float t2 = fminf(d2 * 0.2f, CLIPF);
        float t3 = fminf(d3 * 0.2f, CLIPF);
        float bw = p2 * (float)exp((double)t2);
        float bh = p3 * (float)exp((double)t3);
        float x1 = clampf(cx - 0.5f * bw, 0.0f, CANVASF);
        float y1 = clampf(cy - 0.5f * bh, 0.0f, CANVASF);
        float x2 = clampf(cx + 0.5f * bw, 0.0f, CANVASF);
        float y2 = clampf(cy + 0.5f * bh, 0.0f, CANVASF);
        bool valid = (s > 0.0f) && (x2 > x1) && (y2 > y1);
        s = valid ? s : 0.0f;
        float off = (float)cl * (CANVASF + 1.0f);
        float ox1 = x1 + off, oy1 = y1 + off, ox2 = x2 + off, oy2 = y2 + off;
        s_sc[j] = s;
        s_cl[j] = (float)cl;
        s_keep[j] = valid ? 1 : 0;
        s_bx[j][0] = x1; s_bx[j][1] = y1; s_bx[j][2] = x2; s_bx[j][3] = y2;
        s_ob[j][0] = ox1; s_ob[j][1] = oy1; s_ob[j][2] = ox2; s_ob[j][3] = oy2;
        s_ar[j] = (ox2 - ox1) * (oy2 - oy1);
    }
    __syncthreads();

    for (int i = 0; i < KCAND; i++) {
        int ki = s_keep[i];
        if (ki && tid < KCAND && tid > i) {
            float lx = fmaxf(s_ob[i][0], s_ob[tid][0]);
            float ly = fmaxf(s_ob[i][1], s_ob[tid][1]);
            float rx = fminf(s_ob[i][2], s_ob[tid][2]);
            float ry = fminf(s_ob[i][3], s_ob[tid][3]);
            float iw = fmaxf(rx - lx, 0.0f);
            float ih = fmaxf(ry - ly, 0.0f);
            float inter = iw * ih;
            float iou = inter / (s_ar[i] + s_ar[tid] - inter + 1e-9f);
            if (iou > IOU_THRF) s_keep[tid] = 0;
        }
        __syncthreads();
    }

    if (tid == 0) {
        int pos = 0;
        for (int j = 0; j < KCAND && pos < KOUT; j++)
            if (s_keep[j]) s_fi[pos++] = j;
        for (int j = 0; j < KCAND && pos < KOUT; j++)
            if (!s_keep[j]) s_fi[pos++] = j;
    }
    __syncthreads();

    if (tid < KOUT) {
        int j = s_fi[tid];
        float fs = s_keep[j] ? s_sc[j] : 0.0f;
        size_t o = (size_t)img * KOUT + tid;
        out[o * 4 + 0] = s_bx[j][0];
        out[o * 4 + 1] = s_bx[j][1];
        out[o * 4 + 2] = s_bx[j][2];
        out[o * 4 + 3] = s_bx[j][3];
        out[(size_t)NIMG * KOUT * 4 + o] = fs;
        out[(size_t)NIMG * KOUT * 5 + o] = (fs > 0.0f) ? s_cl[j] : 0.0f;
    }
}

// ---------------------------------------------------------------------------
extern "C" void kernel_launch(void* const* d_in, const int* in_sizes, int n_in,
                              void* d_out, int out_size, void* d_ws, size_t ws_size,
                              hipStream_t stream)
{
    static const int Cin_[6] = {512, 1024, 512, 256, 256, 256};
    static const int lgC_[6] = {9, 10, 9, 8, 8, 8};
    static const int HW_[6]  = {38, 19, 10, 5, 3, 1};
    static const int an_[6]  = {4, 6, 6, 6, 4, 4};
    static const int off_[6] = {0, 5776, 7942, 8542, 8692, 8728};
    // cls weights transposed into scr region: Mp = round16(an*81)
    static const int MpC_[6] = {336, 496, 496, 496, 336, 336};
    static const size_t clsOffF_[6] = {0, 1548288, 6119424, 8404992, 9547776, 10321920};
    // reg weights transposed into hist region (zeroed AFTER conv): Mp = 32
    static const size_t regOffF_[6] = {0, 147456, 442368, 589824, 663552, 737280};

    char* ws = (char*)d_ws;
    const size_t OFF_CLS  = 0;
    const size_t OFF_SCR  = 45266688;
    const size_t OFF_REG  = 89974528;
    const size_t OFF_HIST = 92209920;
    const size_t OFF_CCNT = 96404224;
    const size_t OFF_SEL  = 96404288;
    const size_t OFF_CAND = 96404352;

    float* cls_all = (float*)(ws + OFF_CLS);
    float* scr     = (float*)(ws + OFF_SCR);
    float* reg_all = (float*)(ws + OFF_REG);
    unsigned int* hist    = (unsigned int*)(ws + OFF_HIST);
    unsigned int* candcnt = (unsigned int*)(ws + OFF_CCNT);
    unsigned int* sel     = (unsigned int*)(ws + OFF_SEL);
    uint2* cand           = (uint2*)(ws + OFF_CAND);

    float* wT = scr;             // 44.38 MB <= 44.7 MB scr region
    float* rT = (float*)hist;    // 3.24 MB  <= 4.19 MB hist region

    // ---- weight transposes (cls + reg), before conv ----
    {
        TransJobs tj;
        int ts = 0;
        for (int L = 0; L < 6; L++) {
            tj.src[L] = (const float*)d_in[L * 5 + 1];
            tj.dst[L] = wT + clsOffF_[L];
            tj.Cin[L] = Cin_[L]; tj.lgC[L] = lgC_[L];
            tj.M[L] = an_[L] * TL_CLS; tj.Mp[L] = MpC_[L]; tj.K[L] = Cin_[L] * 9;
            tj.start[L] = ts; ts += Cin_[L] * 9 * 512;
        }
        for (int L = 0; L < 6; L++) {
            int q = 6 + L;
            tj.src[q] = (const float*)d_in[L * 5 + 3];
            tj.dst[q] = rT + regOffF_[L];
            tj.Cin[q] = Cin_[L]; tj.lgC[q] = lgC_[L];
            tj.M[q] = an_[L] * 4; tj.Mp[q] = 32; tj.K[q] = Cin_[L] * 9;
            tj.start[q] = ts; ts += Cin_[L] * 9 * 512;
        }
        tj.total = ts;
        transpose_wgt<<<4096, 256, 0, stream>>>(tj);
    }

    // ---- fused conv: wave-tiles, big jobs first ----
    ConvJobs jobs;
    static const int ord_lvl[12]  = {1, 0, 1, 0, 2, 2, 3, 3, 4, 4, 5, 5};
    static const int ord_iscls[12]= {1, 1, 0, 0, 1, 0, 1, 0, 1, 0, 1, 0};
    int tiles = 0;
    for (int q = 0; q < 12; q++) {
        int L = ord_lvl[q];
        int iscls = ord_iscls[q];
        int an = an_[L];
        jobs.feat[q] = (const float*)d_in[L * 5 + 0];
        jobs.wgtT[q] = iscls ? (wT + clsOffF_[L]) : (rT + regOffF_[L]);
        jobs.bias[q] = (const float*)d_in[L * 5 + (iscls ? 2 : 4)];
        jobs.outp[q] = iscls ? cls_all : reg_all;
        jobs.Cin[q]  = Cin_[L];
        jobs.lgC[q]  = lgC_[L];
        jobs.Hd[q]   = HW_[L];
        jobs.M[q]    = an * (iscls ? TL_CLS : 4);
        jobs.Mp[q]   = iscls ? MpC_[L] : 32;
        jobs.an[q]   = an;
        jobs.off[q]  = off_[L];
        jobs.mi[q]   = iscls ? 2 : 1;
        jobs.tl[q]   = iscls ? TL_CLS : 4;
        int N = NIMG * HW_[L] * HW_[L];
        int nT = (N + 63) / 64;
        int mW = iscls ? (jobs.M[q] + 31) / 32 : (jobs.M[q] + 15) / 16;
        jobs.tileStart[q] = tiles;
        jobs.nT[q] = nT;
        tiles += mW * nT;
    }
    jobs.nJobs = 12;
    jobs.totalTiles = tiles;

    fused_conv<<<(tiles + 3) / 4, 256, 0, stream>>>(jobs);

    // zero hist/candcnt/sel AFTER conv (rT lives in the hist region)
    {
        int nz = NIMG * NBIN + 16 + 16;
        zero_kernel<<<(nz + 255) / 256, 256, 0, stream>>>(hist, nz);
    }

    softmax_kernel<<<(NIMG * A_TOTAL + 63) / 64, 256, 0, stream>>>(cls_all, scr, NIMG * A_TOTAL);
    hist_kernel<<<2048, 256, 0, stream>>>(scr, hist);
    select_kernel<<<NIMG, 1024, 0, stream>>>(hist, sel);
    gather_kernel<<<2048, 256, 0, stream>>>(scr, sel, candcnt, cand);
    nms_kernel<<<NIMG, 1024, 0, stream>>>(cand, candcnt, reg_all,
                                          (const float*)d_in[30], (float*)d_out);
}